// Round 10
// baseline (226.517 us; speedup 1.0000x reference)
//
#include <hip/hip_runtime.h>
#include <math.h>

#define NTOK 198
#define CCH  192
#define DIMV 8

typedef float vf4 __attribute__((ext_vector_type(4)));  // clang-native for nontemporal

__device__ __forceinline__ float qgelu(float v) {
    return v / (1.0f + __expf(-1.702f * v));  // x * sigmoid(1.702 x)
}

// Fully fused: down-proj + qgelu -> conv3x3 + qgelu -> up-proj.
// R10: TWO blocks per batch element (split along conv rows, 1-row halo recomputed),
// 256 threads (4 waves). Grid 2048 -> 4 blocks/CU (16 waves/CU), ~16KB LDS/block.
// (256,4): 128-VGPR cap; R8's identical phase code measured 124 -> fits, no spill.
// R9 lesson: double-buffer + reduce-scatter pinned VGPR at 128 cap -> scratch, FETCH
// +44MB, slower. Keep the simple all-reduce shuffle.
__global__ __launch_bounds__(256, 4) void convpass_fused(
    const float* __restrict__ x,       // [B,198,192]
    const float* __restrict__ w_down,  // [8,192]
    const float* __restrict__ b_down,  // [8]
    const float* __restrict__ conv_w,  // [8,8,3,3]
    const float* __restrict__ conv_b,  // [8]
    const float* __restrict__ w_up,    // [192,8]
    const float* __restrict__ b_up,    // [192]
    float* __restrict__ out)           // [B,198,192]
{
    const int half = blockIdx.x;       // 0: cls+dist+rows 0..6 ; 1: rows 7..13
    const int b    = blockIdx.y;
    const int tid  = threadIdx.x;

    // half 0: outputs n in [0,100), needs d tokens [0,114)   (cls + rows 0..7)
    // half 1: outputs n in [100,198), needs d tokens [86,198) (rows 6..13)
    const int d_start   = half ? 86  : 0;
    const int d_count   = half ? 112 : 114;
    const int out_start = half ? 100 : 0;
    const int out_count = half ? 98  : 100;

    __shared__ float s_w[8 * CCH];    // 6144 B  w_down
    __shared__ float s_d[114 * 9];    // 4104 B  down-proj out (stride 9: conflict-free conv)
    __shared__ float s_d2[100 * 8];   // 3200 B  conv out (stride 8)
    __shared__ float s_cw[576];       // 2304 B  conv weights transposed [kk][i][o]
    __shared__ float s_cb[8];

    // ---- stage weights ----
    for (int t = tid; t < 8 * CCH; t += 256) s_w[t] = w_down[t];
    for (int t = tid; t < 576; t += 256) {
        const int kk = t >> 6, rem = t & 63, i = rem >> 3, o = rem & 7;
        s_cw[t] = conv_w[(o * 8 + i) * 9 + kk];
    }
    if (tid < 8) s_cb[tid] = conv_b[tid];
    __syncthreads();

    // ================= Phase A: d = qgelu(x @ w_down^T + b_down) -> s_d =================
    // wave = 8 tokens x 8 c-chunk lanes; 4 waves x 4 passes cover 128 >= d_count slots.
    {
        const int lane  = tid & 63;
        const int wv    = tid >> 6;       // wave 0..3
        const int t_sub = lane >> 3;      // token-slot 0..7
        const int k     = lane & 7;       // c-chunk (24 floats)
        const float bd  = b_down[k];
        const float* xb = x + (size_t)b * NTOK * CCH;

        #pragma unroll 1
        for (int p = 0; p < 4; ++p) {
            const int idx = p * 32 + wv * 8 + t_sub;   // 0..127 within this half's d range
            const bool valid = (idx < d_count);
            const int n = d_start + (valid ? idx : 0); // safe addr for masked lanes
            const float* xr = xb + (size_t)n * CCH + k * 24;

            float4 xa[6];
            #pragma unroll
            for (int j = 0; j < 6; ++j) xa[j] = *(const float4*)(xr + 4 * j);

            float acc[8] = {0,0,0,0,0,0,0,0};
            #pragma unroll
            for (int j = 0; j < 6; ++j) {
                #pragma unroll
                for (int dm = 0; dm < 8; ++dm) {
                    // 8 distinct addrs/wave (by k), 96B stride, x8 broadcast -> ~2-way: free
                    const float4 wv4 = *(const float4*)&s_w[dm * CCH + k * 24 + j * 4];
                    acc[dm] += xa[j].x * wv4.x + xa[j].y * wv4.y
                             + xa[j].z * wv4.z + xa[j].w * wv4.w;
                }
            }
            float outv = 0.f;
            #pragma unroll
            for (int dm = 0; dm < 8; ++dm) {
                float v = acc[dm];
                v += __shfl_xor(v, 1); v += __shfl_xor(v, 2); v += __shfl_xor(v, 4);
                outv = (dm == k) ? v : outv;
            }
            if (valid) s_d[idx * 9 + k] = qgelu(outv + bd);
        }
    }
    __syncthreads();

    // ================= Phase B: conv3x3 + qgelu -> s_d2 =================
    for (int j = tid; j < out_count * 8; j += 256) {
        const int nr = j >> 3, o = j & 7;
        const int n = out_start + nr;
        if (n == 1) {
            s_d2[j] = 0.0f;            // dist token zeroed; qgelu(0)=0
        } else if (n == 0) {           // cls: center tap only (s_d idx 0 = token 0, half 0)
            float acc = s_cb[o];
            #pragma unroll
            for (int i = 0; i < 8; ++i)
                acc += s_d[i] * s_cw[4 * 64 + i * 8 + o];
            s_d2[j] = qgelu(acc);
        } else {
            const int pos = n - 2, h = pos / 14, w = pos % 14;
            float acc = s_cb[o];
            #pragma unroll
            for (int dh = -1; dh <= 1; ++dh) {
                const int hh = h + dh;
                if (hh < 0 || hh > 13) continue;
                #pragma unroll
                for (int dw = -1; dw <= 1; ++dw) {
                    const int ww = w + dw;
                    if (ww < 0 || ww > 13) continue;
                    const int tok = 2 + hh * 14 + ww;   // in [d_start, d_start+d_count)
                    const int kk  = (dh + 1) * 3 + (dw + 1);
                    const int ti  = tok - d_start;
                    #pragma unroll
                    for (int i = 0; i < 8; ++i)
                        acc += s_d[ti * 9 + i] * s_cw[kk * 64 + i * 8 + o];
                }
            }
            s_d2[j] = qgelu(acc);
        }
    }

    // ---- w_up -> registers (loads issued before the barrier, overlap Phase B)
    const int c4 = tid % 48;
    const int tl = tid / 48;  // 0..5 (tl==5: 16 threads idle in phase C)
    float w_r[4][8];
    #pragma unroll
    for (int cc = 0; cc < 4; ++cc) {
        const float4 wa = *(const float4*)(w_up + (c4 * 4 + cc) * 8);
        const float4 wb = *(const float4*)(w_up + (c4 * 4 + cc) * 8 + 4);
        w_r[cc][0] = wa.x; w_r[cc][1] = wa.y; w_r[cc][2] = wa.z; w_r[cc][3] = wa.w;
        w_r[cc][4] = wb.x; w_r[cc][5] = wb.y; w_r[cc][6] = wb.z; w_r[cc][7] = wb.w;
    }
    const float4 bu = *(const float4*)(b_up + c4 * 4);
    __syncthreads();

    // ================= Phase C: out = d2 @ w_up^T + b_up =================
    if (tl < 5) {
        float* outb = out + ((size_t)b * NTOK + out_start) * CCH;
        #pragma unroll 1
        for (int nr = tl; nr < out_count; nr += 5) {
            const float4 da = *(const float4*)&s_d2[nr * 8];      // broadcast
            const float4 dv = *(const float4*)&s_d2[nr * 8 + 4];
            float accs[4] = {bu.x, bu.y, bu.z, bu.w};
            #pragma unroll
            for (int cc = 0; cc < 4; ++cc) {
                accs[cc] += da.x * w_r[cc][0] + da.y * w_r[cc][1]
                          + da.z * w_r[cc][2] + da.w * w_r[cc][3]
                          + dv.x * w_r[cc][4] + dv.y * w_r[cc][5]
                          + dv.z * w_r[cc][6] + dv.w * w_r[cc][7];
            }
            const vf4 r = {accs[0], accs[1], accs[2], accs[3]};
            __builtin_nontemporal_store(r, (vf4*)(outb + (size_t)nr * CCH + c4 * 4));
        }
    }
}

extern "C" void kernel_launch(void* const* d_in, const int* in_sizes, int n_in,
                              void* d_out, int out_size, void* d_ws, size_t ws_size,
                              hipStream_t stream) {
    const float* x      = (const float*)d_in[0];
    const float* w_down = (const float*)d_in[1];
    const float* b_down = (const float*)d_in[2];
    const float* conv_w = (const float*)d_in[3];
    const float* conv_b = (const float*)d_in[4];
    const float* w_up   = (const float*)d_in[5];
    const float* b_up   = (const float*)d_in[6];
    float* out = (float*)d_out;

    const int B = in_sizes[0] / (NTOK * CCH);   // 1024
    convpass_fused<<<dim3(2, B), dim3(256), 0, stream>>>(
        x, w_down, b_down, conv_w, conv_b, w_up, b_up, out);
}

// Round 11
// 88.960 us; speedup vs baseline: 2.5463x; 2.5463x over previous
//
#include <hip/hip_runtime.h>
#include <math.h>

#define NTOK 198
#define CCH  192
#define DIMV 8

typedef float vf4 __attribute__((ext_vector_type(4)));  // clang-native for nontemporal

__device__ __forceinline__ float qgelu(float v) {
    return v / (1.0f + __expf(-1.702f * v));  // x * sigmoid(1.702 x)
}

// Fully fused: down-proj + qgelu -> conv3x3 + qgelu -> up-proj.
// TWO blocks per batch element (split along conv rows, 1-row halo recomputed),
// 256 threads (4 waves), grid 2048.
// EMPIRICAL launch_bounds rule on this toolchain (R7/R8/R10): VGPR cap = 256/arg2,
// independent of block size. Phase A needs ~124 VGPR -> arg2 MUST be 2.
// HW occupancy then self-limits at floor(512/124)=4 waves/SIMD = 4 blocks/CU.
__global__ __launch_bounds__(256, 2) void convpass_fused(
    const float* __restrict__ x,       // [B,198,192]
    const float* __restrict__ w_down,  // [8,192]
    const float* __restrict__ b_down,  // [8]
    const float* __restrict__ conv_w,  // [8,8,3,3]
    const float* __restrict__ conv_b,  // [8]
    const float* __restrict__ w_up,    // [192,8]
    const float* __restrict__ b_up,    // [192]
    float* __restrict__ out)           // [B,198,192]
{
    const int half = blockIdx.x;       // 0: cls+dist+rows 0..6 ; 1: rows 7..13
    const int b    = blockIdx.y;
    const int tid  = threadIdx.x;

    // half 0: outputs n in [0,100), needs d tokens [0,114)   (cls + rows 0..7)
    // half 1: outputs n in [100,198), needs d tokens [86,198) (rows 6..13)
    const int d_start   = half ? 86  : 0;
    const int d_count   = half ? 112 : 114;
    const int out_start = half ? 100 : 0;
    const int out_count = half ? 98  : 100;

    __shared__ float s_w[8 * CCH];    // 6144 B  w_down
    __shared__ float s_d[114 * 9];    // 4104 B  down-proj out (stride 9: conflict-free conv)
    __shared__ float s_d2[100 * 8];   // 3200 B  conv out (stride 8)
    __shared__ float s_cw[576];       // 2304 B  conv weights transposed [kk][i][o]
    __shared__ float s_cb[8];

    // ---- stage weights ----
    for (int t = tid; t < 8 * CCH; t += 256) s_w[t] = w_down[t];
    for (int t = tid; t < 576; t += 256) {
        const int kk = t >> 6, rem = t & 63, i = rem >> 3, o = rem & 7;
        s_cw[t] = conv_w[(o * 8 + i) * 9 + kk];
    }
    if (tid < 8) s_cb[tid] = conv_b[tid];
    __syncthreads();

    // ================= Phase A: d = qgelu(x @ w_down^T + b_down) -> s_d =================
    // wave = 8 tokens x 8 c-chunk lanes; 4 waves x 4 passes cover 128 >= d_count slots.
    {
        const int lane  = tid & 63;
        const int wv    = tid >> 6;       // wave 0..3
        const int t_sub = lane >> 3;      // token-slot 0..7
        const int k     = lane & 7;       // c-chunk (24 floats)
        const float bd  = b_down[k];
        const float* xb = x + (size_t)b * NTOK * CCH;

        #pragma unroll 1
        for (int p = 0; p < 4; ++p) {
            const int idx = p * 32 + wv * 8 + t_sub;   // 0..127 within this half's d range
            const bool valid = (idx < d_count);
            const int n = d_start + (valid ? idx : 0); // safe addr for masked lanes
            const float* xr = xb + (size_t)n * CCH + k * 24;

            float4 xa[6];
            #pragma unroll
            for (int j = 0; j < 6; ++j) xa[j] = *(const float4*)(xr + 4 * j);

            float acc[8] = {0,0,0,0,0,0,0,0};
            #pragma unroll
            for (int j = 0; j < 6; ++j) {
                #pragma unroll
                for (int dm = 0; dm < 8; ++dm) {
                    // 8 distinct addrs/wave (by k), 96B stride, x8 broadcast -> ~2-way: free
                    const float4 wv4 = *(const float4*)&s_w[dm * CCH + k * 24 + j * 4];
                    acc[dm] += xa[j].x * wv4.x + xa[j].y * wv4.y
                             + xa[j].z * wv4.z + xa[j].w * wv4.w;
                }
            }
            float outv = 0.f;
            #pragma unroll
            for (int dm = 0; dm < 8; ++dm) {
                float v = acc[dm];
                v += __shfl_xor(v, 1); v += __shfl_xor(v, 2); v += __shfl_xor(v, 4);
                outv = (dm == k) ? v : outv;
            }
            if (valid) s_d[idx * 9 + k] = qgelu(outv + bd);
        }
    }
    __syncthreads();

    // ================= Phase B: conv3x3 + qgelu -> s_d2 =================
    for (int j = tid; j < out_count * 8; j += 256) {
        const int nr = j >> 3, o = j & 7;
        const int n = out_start + nr;
        if (n == 1) {
            s_d2[j] = 0.0f;            // dist token zeroed; qgelu(0)=0
        } else if (n == 0) {           // cls: center tap only (s_d idx 0 = token 0, half 0)
            float acc = s_cb[o];
            #pragma unroll
            for (int i = 0; i < 8; ++i)
                acc += s_d[i] * s_cw[4 * 64 + i * 8 + o];
            s_d2[j] = qgelu(acc);
        } else {
            const int pos = n - 2, h = pos / 14, w = pos % 14;
            float acc = s_cb[o];
            #pragma unroll
            for (int dh = -1; dh <= 1; ++dh) {
                const int hh = h + dh;
                if (hh < 0 || hh > 13) continue;
                #pragma unroll
                for (int dw = -1; dw <= 1; ++dw) {
                    const int ww = w + dw;
                    if (ww < 0 || ww > 13) continue;
                    const int tok = 2 + hh * 14 + ww;   // in [d_start, d_start+d_count)
                    const int kk  = (dh + 1) * 3 + (dw + 1);
                    const int ti  = tok - d_start;
                    #pragma unroll
                    for (int i = 0; i < 8; ++i)
                        acc += s_d[ti * 9 + i] * s_cw[kk * 64 + i * 8 + o];
                }
            }
            s_d2[j] = qgelu(acc);
        }
    }

    // ---- w_up -> registers (loads issued before the barrier, overlap Phase B)
    const int c4 = tid % 48;
    const int tl = tid / 48;  // 0..5 (tl==5: 16 threads idle in phase C)
    float w_r[4][8];
    #pragma unroll
    for (int cc = 0; cc < 4; ++cc) {
        const float4 wa = *(const float4*)(w_up + (c4 * 4 + cc) * 8);
        const float4 wb = *(const float4*)(w_up + (c4 * 4 + cc) * 8 + 4);
        w_r[cc][0] = wa.x; w_r[cc][1] = wa.y; w_r[cc][2] = wa.z; w_r[cc][3] = wa.w;
        w_r[cc][4] = wb.x; w_r[cc][5] = wb.y; w_r[cc][6] = wb.z; w_r[cc][7] = wb.w;
    }
    const float4 bu = *(const float4*)(b_up + c4 * 4);
    __syncthreads();

    // ================= Phase C: out = d2 @ w_up^T + b_up =================
    if (tl < 5) {
        float* outb = out + ((size_t)b * NTOK + out_start) * CCH;
        #pragma unroll 1
        for (int nr = tl; nr < out_count; nr += 5) {
            const float4 da = *(const float4*)&s_d2[nr * 8];      // broadcast
            const float4 dv = *(const float4*)&s_d2[nr * 8 + 4];
            float accs[4] = {bu.x, bu.y, bu.z, bu.w};
            #pragma unroll
            for (int cc = 0; cc < 4; ++cc) {
                accs[cc] += da.x * w_r[cc][0] + da.y * w_r[cc][1]
                          + da.z * w_r[cc][2] + da.w * w_r[cc][3]
                          + dv.x * w_r[cc][4] + dv.y * w_r[cc][5]
                          + dv.z * w_r[cc][6] + dv.w * w_r[cc][7];
            }
            const vf4 r = {accs[0], accs[1], accs[2], accs[3]};
            __builtin_nontemporal_store(r, (vf4*)(outb + (size_t)nr * CCH + c4 * 4));
        }
    }
}

extern "C" void kernel_launch(void* const* d_in, const int* in_sizes, int n_in,
                              void* d_out, int out_size, void* d_ws, size_t ws_size,
                              hipStream_t stream) {
    const float* x      = (const float*)d_in[0];
    const float* w_down = (const float*)d_in[1];
    const float* b_down = (const float*)d_in[2];
    const float* conv_w = (const float*)d_in[3];
    const float* conv_b = (const float*)d_in[4];
    const float* w_up   = (const float*)d_in[5];
    const float* b_up   = (const float*)d_in[6];
    float* out = (float*)d_out;

    const int B = in_sizes[0] / (NTOK * CCH);   // 1024
    convpass_fused<<<dim3(2, B), dim3(256), 0, stream>>>(
        x, w_down, b_down, conv_w, conv_b, w_up, b_up, out);
}

// Round 12
// 82.917 us; speedup vs baseline: 2.7318x; 1.0729x over previous
//
#include <hip/hip_runtime.h>
#include <math.h>

#define NTOK 198
#define CCH  192

typedef float vf4 __attribute__((ext_vector_type(4)));  // clang-native for nontemporal

__device__ __forceinline__ float qgelu(float v) {
    return v / (1.0f + __expf(-1.702f * v));  // x * sigmoid(1.702 x)
}

__device__ __forceinline__ float dot8(const float4& a, const float4& wa,
                                      const float4& b, const float4& wb) {
    return a.x*wa.x + a.y*wa.y + a.z*wa.z + a.w*wa.w
         + b.x*wb.x + b.y*wb.y + b.z*wb.z + b.w*wb.w;
}

// Fully fused: down-proj + qgelu -> conv3x3 + qgelu -> up-proj.
// TWO blocks per batch element (split along conv rows, halo recomputed), 256 thr.
// (256,2): VGPR cap 128 (empirical rule: cap = 256/arg2; arg2>=4 => 64 => spill).
// R12: LDS-instruction diet. Phase A computes 2 tokens per lane per w-fragment
// (192->96 ds_read_b128/thread); Phase B reads d-rows and cw-slices as float4
// (s_d stride 8, s_cw [kk][o][i]) (450->~112 LDS instr/thread).
__global__ __launch_bounds__(256, 2) void convpass_fused(
    const float* __restrict__ x,       // [B,198,192]
    const float* __restrict__ w_down,  // [8,192]
    const float* __restrict__ b_down,  // [8]
    const float* __restrict__ conv_w,  // [8,8,3,3]
    const float* __restrict__ conv_b,  // [8]
    const float* __restrict__ w_up,    // [192,8]
    const float* __restrict__ b_up,    // [192]
    float* __restrict__ out)           // [B,198,192]
{
    const int half = blockIdx.x;       // 0: cls+dist+rows 0..6 ; 1: rows 7..13
    const int b    = blockIdx.y;
    const int tid  = threadIdx.x;

    // half 0: outputs n in [0,100), needs d tokens [0,114)   (cls+dist+rows 0..7)
    // half 1: outputs n in [100,198), needs d tokens [86,198) (rows 6..13)
    const int d_start   = half ? 86  : 0;
    const int d_count   = half ? 112 : 114;
    const int out_start = half ? 100 : 0;
    const int out_count = half ? 98  : 100;

    __shared__ float s_w[8 * CCH];    // 6144 B  w_down
    __shared__ float s_d[114 * 8];    // 3648 B  down-proj out (stride 8: b128 rows)
    __shared__ float s_d2[100 * 8];   // 3200 B  conv out
    __shared__ float s_cw[576];       // 2304 B  conv weights [kk][o][i]

    // ---- stage weights ----
    for (int t = tid; t < 8 * CCH; t += 256) s_w[t] = w_down[t];
    for (int t = tid; t < 576; t += 256) {
        const int kk = t >> 6, rem = t & 63, o = rem >> 3, i = rem & 7;
        s_cw[t] = conv_w[(o * 8 + i) * 9 + kk];   // [kk][o][i] <- [o][i][kk]
    }
    __syncthreads();

    // ========== Phase A: d = qgelu(x @ w_down^T + b_down) -> s_d ==========
    // wave = 8 token-slots x 8 c-chunk lanes, TWO rows per lane (w-fragment reuse).
    // 4 waves x 16 rows x 2 passes = 128 >= d_count.
    {
        const int lane  = tid & 63;
        const int wv    = tid >> 6;       // wave 0..3
        const int t_sub = lane >> 3;      // token-slot 0..7
        const int k     = lane & 7;       // c-chunk (24 floats)
        const float bd  = b_down[k];
        const float* xb = x + (size_t)b * NTOK * CCH;

        #pragma unroll 1
        for (int p = 0; p < 2; ++p) {
            const int g  = p * 64 + wv * 16;
            const int iA = g + t_sub;
            const int iB = iA + 8;
            const bool vA = (iA < d_count), vB = (iB < d_count);
            const int nA = d_start + (vA ? iA : 0);   // safe addr for masked lanes
            const int nB = d_start + (vB ? iB : 0);
            const float* pA = xb + (size_t)nA * CCH + k * 24;
            const float* pB = xb + (size_t)nB * CCH + k * 24;

            float accA[8] = {0,0,0,0,0,0,0,0};
            float accB[8] = {0,0,0,0,0,0,0,0};
            #pragma unroll
            for (int h2 = 0; h2 < 2; ++h2) {          // 12-float sub-steps
                float4 xa[3], xv[3];
                #pragma unroll
                for (int j = 0; j < 3; ++j) {
                    xa[j] = *(const float4*)(pA + h2 * 12 + 4 * j);
                    xv[j] = *(const float4*)(pB + h2 * 12 + 4 * j);
                }
                #pragma unroll
                for (int j = 0; j < 3; ++j) {
                    const int c = k * 24 + h2 * 12 + j * 4;
                    #pragma unroll
                    for (int dm = 0; dm < 8; ++dm) {
                        // 8 distinct addrs/wave (k), 96B stride -> 2-way: free
                        const float4 wv4 = *(const float4*)&s_w[dm * CCH + c];
                        accA[dm] += xa[j].x*wv4.x + xa[j].y*wv4.y + xa[j].z*wv4.z + xa[j].w*wv4.w;
                        accB[dm] += xv[j].x*wv4.x + xv[j].y*wv4.y + xv[j].z*wv4.z + xv[j].w*wv4.w;
                    }
                }
            }
            float oA = 0.f, oB = 0.f;
            #pragma unroll
            for (int dm = 0; dm < 8; ++dm) {
                float a = accA[dm];
                a += __shfl_xor(a, 1); a += __shfl_xor(a, 2); a += __shfl_xor(a, 4);
                float c = accB[dm];
                c += __shfl_xor(c, 1); c += __shfl_xor(c, 2); c += __shfl_xor(c, 4);
                oA = (dm == k) ? a : oA;
                oB = (dm == k) ? c : oB;
            }
            // writes: 64 consecutive floats per wave -> 2-way banks: free
            if (vA) s_d[iA * 8 + k] = qgelu(oA + bd);
            if (vB) s_d[iB * 8 + k] = qgelu(oB + bd);
        }
    }
    __syncthreads();

    // ========== Phase B: conv3x3 + qgelu -> s_d2 (b128 reads) ==========
    for (int j = tid; j < out_count * 8; j += 256) {
        const int nr = j >> 3, o = j & 7;
        const int n = out_start + nr;
        if (n == 1) {
            s_d2[j] = 0.0f;            // dist token zeroed; qgelu(0)=0
        } else if (n == 0) {           // cls: center tap only (half 0: s_d idx0 = tok 0)
            const float4 d0 = *(const float4*)&s_d[0];
            const float4 d1 = *(const float4*)&s_d[4];
            const float4 w0 = *(const float4*)&s_cw[4 * 64 + o * 8];
            const float4 w1 = *(const float4*)&s_cw[4 * 64 + o * 8 + 4];
            s_d2[j] = qgelu(conv_b[o] + dot8(d0, w0, d1, w1));
        } else {
            const int pos = n - 2, h = pos / 14, w = pos % 14;
            float acc = conv_b[o];
            #pragma unroll
            for (int dh = -1; dh <= 1; ++dh) {
                const int hh = h + dh;
                if (hh < 0 || hh > 13) continue;
                #pragma unroll
                for (int dw = -1; dw <= 1; ++dw) {
                    const int ww = w + dw;
                    if (ww < 0 || ww > 13) continue;
                    const int tok = 2 + hh * 14 + ww;
                    const int kk  = (dh + 1) * 3 + (dw + 1);
                    const int ti  = tok - d_start;
                    // 8 distinct rows at 32B stride -> 2-way banks: free
                    const float4 d0 = *(const float4*)&s_d[ti * 8];
                    const float4 d1 = *(const float4*)&s_d[ti * 8 + 4];
                    const float4 w0 = *(const float4*)&s_cw[kk * 64 + o * 8];
                    const float4 w1 = *(const float4*)&s_cw[kk * 64 + o * 8 + 4];
                    acc += dot8(d0, w0, d1, w1);
                }
            }
            s_d2[j] = qgelu(acc);
        }
    }
    __syncthreads();

    // ========== Phase C: out = d2 @ w_up^T + b_up ==========
    const int c4 = tid % 48;
    const int tl = tid / 48;  // 0..5 (tl==5: 16 threads idle)
    if (tl < 5) {
        float w_r[4][8];
        #pragma unroll
        for (int cc = 0; cc < 4; ++cc) {
            const float4 wa = *(const float4*)(w_up + (c4 * 4 + cc) * 8);
            const float4 wb = *(const float4*)(w_up + (c4 * 4 + cc) * 8 + 4);
            w_r[cc][0] = wa.x; w_r[cc][1] = wa.y; w_r[cc][2] = wa.z; w_r[cc][3] = wa.w;
            w_r[cc][4] = wb.x; w_r[cc][5] = wb.y; w_r[cc][6] = wb.z; w_r[cc][7] = wb.w;
        }
        const float4 bu = *(const float4*)(b_up + c4 * 4);
        float* outb = out + ((size_t)b * NTOK + out_start) * CCH;
        #pragma unroll 1
        for (int nr = tl; nr < out_count; nr += 5) {
            const float4 da = *(const float4*)&s_d2[nr * 8];      // broadcast
            const float4 dv = *(const float4*)&s_d2[nr * 8 + 4];
            float accs[4] = {bu.x, bu.y, bu.z, bu.w};
            #pragma unroll
            for (int cc = 0; cc < 4; ++cc) {
                accs[cc] += da.x * w_r[cc][0] + da.y * w_r[cc][1]
                          + da.z * w_r[cc][2] + da.w * w_r[cc][3]
                          + dv.x * w_r[cc][4] + dv.y * w_r[cc][5]
                          + dv.z * w_r[cc][6] + dv.w * w_r[cc][7];
            }
            const vf4 r = {accs[0], accs[1], accs[2], accs[3]};
            __builtin_nontemporal_store(r, (vf4*)(outb + (size_t)nr * CCH + c4 * 4));
        }
    }
}

extern "C" void kernel_launch(void* const* d_in, const int* in_sizes, int n_in,
                              void* d_out, int out_size, void* d_ws, size_t ws_size,
                              hipStream_t stream) {
    const float* x      = (const float*)d_in[0];
    const float* w_down = (const float*)d_in[1];
    const float* b_down = (const float*)d_in[2];
    const float* conv_w = (const float*)d_in[3];
    const float* conv_b = (const float*)d_in[4];
    const float* w_up   = (const float*)d_in[5];
    const float* b_up   = (const float*)d_in[6];
    float* out = (float*)d_out;

    const int B = in_sizes[0] / (NTOK * CCH);   // 1024
    convpass_fused<<<dim3(2, B), dim3(256), 0, stream>>>(
        x, w_down, b_down, conv_w, conv_b, w_up, b_up, out);
}